// Round 13
// baseline (103.913 us; speedup 1.0000x reference)
//
#include <hip/hip_runtime.h>
#include <hip/hip_fp16.h>

// MinibatchDiscrimination  B=256, IN_F=1024, OUT_F=128, KD=16 (fp32 in/out)
// out[b] = concat(x[b], o_b[b]); o_b[b][o] = sum_b2 exp(-L1(m[b,o,:], m[b2,o,:])) - 1
//
// R13: k_pair rebuilt for SERIAL-CHAIN overlap (R12 post-mortem: all
// throughput floors are 2-5 us/kernel vs ~9 us measured — after fixing the
// 4-SIMD/CU error in the VALU model, no pipe is the binder; the residual is
// the per-block load->barrier->compute->barrier chain at 1 block/CU).
//   - 512 blocks (o, b1-quarter) x 512 thr = 2 blocks/CU: chains overlap.
//   - Sl2 computed from registers during the pm load (no extra barrier/pass).
//   - 2 barriers (was 3), no prologue x-copy (moved to k_prep), 4 rows x 8 b2
//     per thread, co reads <=4-way LDS aliased.
//   - k_pair launched x3 (idempotent): dur arithmetic pins new p' exactly;
//     R14 dedups. dur13 = 92.9 - p12 + 3p' -> 93-97 if chain fix works.
// Numerics: min-trick arg folded to exp2; self-pair residual = 2*eps*ulp ->
// absmax ~4e-5 (R12 measured 4.22e-5, matches model) << 0.099.

#define BATCH 256
#define INF   1024
#define OUTF  128
#define KDIM  16
#define TCOLS 2048
#define OCOLS 1152

typedef __attribute__((ext_vector_type(8))) short short8;
typedef __attribute__((ext_vector_type(4))) float f32x4;

#define L2E  1.4426950408889634f
#define TL2E 2.8853900817779268f   // exactly 2*fp32(L2E): pow2 scaling is exact

__device__ inline unsigned short bf_trunc(float f) {
    return (unsigned short)(__float_as_uint(f) >> 16);
}
__device__ inline unsigned pack_bf2(float lo, float hi) {
    return __builtin_amdgcn_perm(__float_as_uint(hi), __float_as_uint(lo), 0x07060302u);
}
// packed f16 min: instruction exists on gfx950, HIP wrapper doesn't (ROCm 7.2)
__device__ inline __half2 hmin2(__half2 a, __half2 b) {
    unsigned ua = *reinterpret_cast<unsigned*>(&a);
    unsigned ub = *reinterpret_cast<unsigned*>(&b);
    unsigned ud;
    asm("v_pk_min_f16 %0, %1, %2" : "=v"(ud) : "v"(ua), "v"(ub));
    return *reinterpret_cast<__half2*>(&ud);
}
// sum over 16 halfs of min(A,B), FIXED op order (used with A==B for the S
// precompute so the self-pair cancels to ~ulp).
__device__ inline float ms_chain(const __half2* A, const __half2* B) {
    __half2 m0 = hmin2(A[0], B[0]);
    __half2 m1 = hmin2(A[1], B[1]);
    __half2 m2 = hmin2(A[2], B[2]);
    __half2 m3 = hmin2(A[3], B[3]);
    m0 = __hadd2(m0, hmin2(A[4], B[4]));
    m1 = __hadd2(m1, hmin2(A[5], B[5]));
    m2 = __hadd2(m2, hmin2(A[6], B[6]));
    m3 = __hadd2(m3, hmin2(A[7], B[7]));
    __half2 es = __hadd2(__hadd2(m0, m1), __hadd2(m2, m3));
    return __low2float(es) + __high2float(es);
}

// ---------------------------------------------------------------- k_prep
// blocks [0,512): transpose+cvt T -> tt[2048][1024] bf16; [512,576): x -> xb;
// [576,864): out x-copy + nothing else (tail written by k_pair).
#define TPAD 66
__global__ __launch_bounds__(256) void k_prep(const float* __restrict__ x,
                                              const float* __restrict__ T,
                                              unsigned short* __restrict__ xb,
                                              unsigned short* __restrict__ tt,
                                              float* __restrict__ out) {
    __shared__ unsigned short sm[64][TPAD];
    const int blk = blockIdx.x, tid = threadIdx.x;
    if (blk < 512) {
        const int k0 = (blk & 15) * 64, n0 = (blk >> 4) * 64;
        {   // coalesced read: 64 k-rows x 64 n-cols
            const int r = tid >> 2, cg = (tid & 3) * 16;
            const float* src = &T[(k0 + r) * TCOLS + n0 + cg];
            #pragma unroll
            for (int u = 0; u < 4; ++u) {
                float4 v = *reinterpret_cast<const float4*>(src + u * 4);
                sm[r][cg + u*4 + 0] = bf_trunc(v.x);
                sm[r][cg + u*4 + 1] = bf_trunc(v.y);
                sm[r][cg + u*4 + 2] = bf_trunc(v.z);
                sm[r][cg + u*4 + 3] = bf_trunc(v.w);
            }
        }
        __syncthreads();
        {   // coalesced write: 64 n-rows x 64 k-cols
            const int n = tid >> 2, kg = (tid & 3) * 16;
            unsigned int pk[8];
            #pragma unroll
            for (int j = 0; j < 8; ++j)
                pk[j] = (unsigned int)sm[kg + 2*j][n] |
                        ((unsigned int)sm[kg + 2*j + 1][n] << 16);
            uint4* dst = reinterpret_cast<uint4*>(&tt[(n0 + n) * INF + k0 + kg]);
            dst[0] = make_uint4(pk[0], pk[1], pk[2], pk[3]);
            dst[1] = make_uint4(pk[4], pk[5], pk[6], pk[7]);
        }
    } else if (blk < 576) {
        const int base = (blk - 512) * 4096 + tid * 16;
        unsigned int pk[8];
        #pragma unroll
        for (int u = 0; u < 4; ++u) {
            float4 v = *reinterpret_cast<const float4*>(&x[base + u * 4]);
            pk[u*2]   = pack_bf2(v.x, v.y);
            pk[u*2+1] = pack_bf2(v.z, v.w);
        }
        uint4* dst = reinterpret_cast<uint4*>(&xb[base]);
        dst[0] = make_uint4(pk[0], pk[1], pk[2], pk[3]);
        dst[1] = make_uint4(pk[4], pk[5], pk[6], pk[7]);
    } else {
        const int t2 = (blk - 576) * 256 + tid;        // 0..73727
        const int b = t2 / 288, c4 = t2 - b * 288;
        if (c4 < 256)
            reinterpret_cast<float4*>(out)[b * 288 + c4] =
                reinterpret_cast<const float4*>(x)[b * 256 + c4];
        // tail columns written by k_pair (direct store) — no init needed
    }
}

// ---------------------------------------------------------------- k_gemm
// [byte-identical to R12] Block = (o, mq), 256 thr = 4 waves; wave w ->
// 16x16 m-tile mq*4+w. All-bf16, no LDS staging in K-loop.
__global__ __launch_bounds__(256) void k_gemm(const unsigned short* __restrict__ xb,
                                              const unsigned short* __restrict__ tt,
                                              __half* __restrict__ mh) {
    const int blk = blockIdx.x;
    const int o   = blk & 127;
    const int mq  = blk >> 7;
    const int tid = threadIdx.x;
    const int wave = tid >> 6, lane = tid & 63;
    const int l15 = lane & 15, q = lane >> 4;

    __shared__ __half pmout[64][16];     // 2 KB repack buffer

    const int mt = mq * 4 + wave;
    const short8* ap = reinterpret_cast<const short8*>(&xb[(mt * 16 + l15) * INF + q * 8]);
    const short8* bp = reinterpret_cast<const short8*>(&tt[(o * 16 + l15) * INF + q * 8]);

    f32x4 acc = {0.f, 0.f, 0.f, 0.f};
    #pragma unroll 8
    for (int ks = 0; ks < 32; ++ks) {
        short8 a = ap[ks * 4];           // advance 32 k = 4 short8
        short8 b = bp[ks * 4];
        acc = __builtin_amdgcn_mfma_f32_16x16x32_bf16(a, b, acc, 0, 0, 0);
    }

    #pragma unroll
    for (int r = 0; r < 4; ++r)
        pmout[wave * 16 + q * 4 + r][l15] = __float2half(acc[r]);
    __syncthreads();

    if (tid < 128) {
        const int row = tid >> 1, hh = tid & 1;
        uint4 v = *reinterpret_cast<const uint4*>(&pmout[row][hh * 8]);
        *reinterpret_cast<uint4*>(&mh[o * (BATCH * KDIM) + (mq * 64 + row) * KDIM + hh * 8]) = v;
    }
}

// ---------------------------------------------------------------- k_pair (rebuilt)
// 512 blocks = (o = blk&127, qh = blk>>7 in 0..3) x 512 thr = 2 blocks/CU.
// Thread (wave w, lane l): i1 = l&15 -> 4 b1-rows {qh*64 + r*16 + i1};
// bsel = w*4 + (l>>4) in 0..31 -> b2 in [bsel*8, bsel*8+8).
// Loader threads (<256) compute Sl2 from registers during the pm load.
// 2 barriers total. Launched x3 this round (idempotent) to pin p'.
__global__ __launch_bounds__(512) void k_pair(const __half* __restrict__ mh,
                                              float* __restrict__ out) {
    const int blk = blockIdx.x;
    const int o   = blk & 127;
    const int qh  = blk >> 7;            // b1 quarter
    const int tid = threadIdx.x;
    const int lane = tid & 63, wave = tid >> 6;

    __shared__ __half2 pm[BATCH][8];     // 8 KB
    __shared__ float Sl2[BATCH];         // 1 KB
    __shared__ float part[32][64];       // 8 KB [bsel][row-local]

    // load pm (full 256x16 slice, coalesced 2x dwordx4/thread) + S from regs
    if (tid < 256) {
        union { uint4 u[2]; __half2 hh[8]; } c;
        const uint4* src = reinterpret_cast<const uint4*>(&mh[o * (BATCH * KDIM) + tid * KDIM]);
        c.u[0] = src[0];
        c.u[1] = src[1];
        *reinterpret_cast<uint4*>(&pm[tid][0]) = c.u[0];
        *reinterpret_cast<uint4*>(&pm[tid][4]) = c.u[1];
        Sl2[tid] = L2E * ms_chain(c.hh, c.hh);   // min(a,a)=a: same chain order
    }
    __syncthreads();                     // barrier 1

    const int i1 = lane & 15;
    const int bsel = wave * 4 + (lane >> 4);     // 0..31, <=4-way co aliasing
    __half2 my[4][8];
    float ns[4];
    #pragma unroll
    for (int r = 0; r < 4; ++r) {
        const int b1 = qh * 64 + r * 16 + i1;
        union { uint4 u[2]; __half2 hh[8]; } c;
        c.u[0] = *reinterpret_cast<const uint4*>(&pm[b1][0]);
        c.u[1] = *reinterpret_cast<const uint4*>(&pm[b1][4]);
        #pragma unroll
        for (int j = 0; j < 8; ++j) my[r][j] = c.hh[j];
        ns[r] = -Sl2[b1];
    }

    float tot[4] = {0.f, 0.f, 0.f, 0.f};
    const int b2_lo = bsel * 8;
    #pragma unroll
    for (int b2 = b2_lo; b2 < b2_lo + 8; ++b2) {
        union { uint4 u[2]; __half2 hh[8]; } co;
        co.u[0] = *reinterpret_cast<const uint4*>(&pm[b2][0]);
        co.u[1] = *reinterpret_cast<const uint4*>(&pm[b2][4]);
        const float sb2 = Sl2[b2];
        #pragma unroll
        for (int r = 0; r < 4; ++r) {
            float msf = ms_chain(my[r], co.hh);
            // exp(-(S1+S2-2ms)) = exp2(2*L2E*ms - L2E*S1 - L2E*S2)
            float arg = fmaf(TL2E, msf, ns[r] - sb2);
            tot[r] += __builtin_amdgcn_exp2f(arg);   // self-pair: arg ~ ±ulp -> ~1
        }
    }
    #pragma unroll
    for (int r = 0; r < 4; ++r)
        part[bsel][r * 16 + i1] = tot[r];
    __syncthreads();                     // barrier 2

    // epilogue: 64 rows, sum 32 partials; -1 removes self-pair.
    if (tid < 64) {
        float s = -1.0f;
        #pragma unroll
        for (int j = 0; j < 32; ++j) s += part[j][tid];
        out[(qh * 64 + tid) * OCOLS + INF + o] = s;
    }
}

// ---------------------------------------------------------------- launch
// MEASUREMENT: k_pair x3 (idempotent, deterministic stores). R14 dedups:
// p' = (dur13 - dur14 - 4.4)/2 closes the books.
extern "C" void kernel_launch(void* const* d_in, const int* in_sizes, int n_in,
                              void* d_out, int out_size, void* d_ws, size_t ws_size,
                              hipStream_t stream) {
    const float* x = (const float*)d_in[0];   // [256][1024]
    const float* T = (const float*)d_in[1];   // [1024][2048]
    float* out = (float*)d_out;               // [256][1152]

    unsigned short* xb = (unsigned short*)d_ws;                              // 512 KB
    unsigned short* tt = (unsigned short*)((char*)d_ws + (512u << 10));      // 4 MB
    __half*         mh = (__half*)((char*)d_ws + (512u << 10) + (4u << 20)); // 1 MB

    k_prep<<<864, 256, 0, stream>>>(x, T, xb, tt, out);
    k_gemm<<<512, 256, 0, stream>>>(xb, tt, mh);
    k_pair<<<512, 512, 0, stream>>>(mh, out);
    k_pair<<<512, 512, 0, stream>>>(mh, out);
    k_pair<<<512, 512, 0, stream>>>(mh, out);
}

// Round 14
// 88.168 us; speedup vs baseline: 1.1786x; 1.1786x over previous
//
#include <hip/hip_runtime.h>
#include <hip/hip_fp16.h>

// MinibatchDiscrimination  B=256, IN_F=1024, OUT_F=128, KD=16 (fp32 in/out)
// out[b] = concat(x[b], o_b[b]); o_b[b][o] = sum_b2 exp(-L1(m[b,o,:], m[b2,o,:])) - 1
//
// R14 = R13 with the two redundant k_pair launches removed (kernels
// byte-identical). Dual purpose: best-known config AND final book-closing
// measurement: p' = (dur13 - dur14 - 4.4)/2, gemm = dur14 - 60.5 - prep - p'.
// Session model: harness-fixed base ~60.5 us (43.5 ws-fill + small fills +
// 7x2.2 node gaps); observed ~5-7 us per-dispatch exec floor on this problem.
// Numerics: min-trick self-pair residual -> absmax 4.22e-5 (measured R12/R13,
// matches 2*eps*ulp model) << 0.099 threshold.

#define BATCH 256
#define INF   1024
#define OUTF  128
#define KDIM  16
#define TCOLS 2048
#define OCOLS 1152

typedef __attribute__((ext_vector_type(8))) short short8;
typedef __attribute__((ext_vector_type(4))) float f32x4;

#define L2E  1.4426950408889634f
#define TL2E 2.8853900817779268f   // exactly 2*fp32(L2E): pow2 scaling is exact

__device__ inline unsigned short bf_trunc(float f) {
    return (unsigned short)(__float_as_uint(f) >> 16);
}
__device__ inline unsigned pack_bf2(float lo, float hi) {
    return __builtin_amdgcn_perm(__float_as_uint(hi), __float_as_uint(lo), 0x07060302u);
}
// packed f16 min: instruction exists on gfx950, HIP wrapper doesn't (ROCm 7.2)
__device__ inline __half2 hmin2(__half2 a, __half2 b) {
    unsigned ua = *reinterpret_cast<unsigned*>(&a);
    unsigned ub = *reinterpret_cast<unsigned*>(&b);
    unsigned ud;
    asm("v_pk_min_f16 %0, %1, %2" : "=v"(ud) : "v"(ua), "v"(ub));
    return *reinterpret_cast<__half2*>(&ud);
}
// sum over 16 halfs of min(A,B), FIXED op order (used with A==B for the S
// precompute so the self-pair cancels to ~ulp).
__device__ inline float ms_chain(const __half2* A, const __half2* B) {
    __half2 m0 = hmin2(A[0], B[0]);
    __half2 m1 = hmin2(A[1], B[1]);
    __half2 m2 = hmin2(A[2], B[2]);
    __half2 m3 = hmin2(A[3], B[3]);
    m0 = __hadd2(m0, hmin2(A[4], B[4]));
    m1 = __hadd2(m1, hmin2(A[5], B[5]));
    m2 = __hadd2(m2, hmin2(A[6], B[6]));
    m3 = __hadd2(m3, hmin2(A[7], B[7]));
    __half2 es = __hadd2(__hadd2(m0, m1), __hadd2(m2, m3));
    return __low2float(es) + __high2float(es);
}

// ---------------------------------------------------------------- k_prep
// blocks [0,512): transpose+cvt T -> tt[2048][1024] bf16; [512,576): x -> xb;
// [576,864): out x-copy.
#define TPAD 66
__global__ __launch_bounds__(256) void k_prep(const float* __restrict__ x,
                                              const float* __restrict__ T,
                                              unsigned short* __restrict__ xb,
                                              unsigned short* __restrict__ tt,
                                              float* __restrict__ out) {
    __shared__ unsigned short sm[64][TPAD];
    const int blk = blockIdx.x, tid = threadIdx.x;
    if (blk < 512) {
        const int k0 = (blk & 15) * 64, n0 = (blk >> 4) * 64;
        {   // coalesced read: 64 k-rows x 64 n-cols
            const int r = tid >> 2, cg = (tid & 3) * 16;
            const float* src = &T[(k0 + r) * TCOLS + n0 + cg];
            #pragma unroll
            for (int u = 0; u < 4; ++u) {
                float4 v = *reinterpret_cast<const float4*>(src + u * 4);
                sm[r][cg + u*4 + 0] = bf_trunc(v.x);
                sm[r][cg + u*4 + 1] = bf_trunc(v.y);
                sm[r][cg + u*4 + 2] = bf_trunc(v.z);
                sm[r][cg + u*4 + 3] = bf_trunc(v.w);
            }
        }
        __syncthreads();
        {   // coalesced write: 64 n-rows x 64 k-cols
            const int n = tid >> 2, kg = (tid & 3) * 16;
            unsigned int pk[8];
            #pragma unroll
            for (int j = 0; j < 8; ++j)
                pk[j] = (unsigned int)sm[kg + 2*j][n] |
                        ((unsigned int)sm[kg + 2*j + 1][n] << 16);
            uint4* dst = reinterpret_cast<uint4*>(&tt[(n0 + n) * INF + k0 + kg]);
            dst[0] = make_uint4(pk[0], pk[1], pk[2], pk[3]);
            dst[1] = make_uint4(pk[4], pk[5], pk[6], pk[7]);
        }
    } else if (blk < 576) {
        const int base = (blk - 512) * 4096 + tid * 16;
        unsigned int pk[8];
        #pragma unroll
        for (int u = 0; u < 4; ++u) {
            float4 v = *reinterpret_cast<const float4*>(&x[base + u * 4]);
            pk[u*2]   = pack_bf2(v.x, v.y);
            pk[u*2+1] = pack_bf2(v.z, v.w);
        }
        uint4* dst = reinterpret_cast<uint4*>(&xb[base]);
        dst[0] = make_uint4(pk[0], pk[1], pk[2], pk[3]);
        dst[1] = make_uint4(pk[4], pk[5], pk[6], pk[7]);
    } else {
        const int t2 = (blk - 576) * 256 + tid;        // 0..73727
        const int b = t2 / 288, c4 = t2 - b * 288;
        if (c4 < 256)
            reinterpret_cast<float4*>(out)[b * 288 + c4] =
                reinterpret_cast<const float4*>(x)[b * 256 + c4];
        // tail columns written by k_pair (direct store) — no init needed
    }
}

// ---------------------------------------------------------------- k_gemm
// [byte-identical to R12/R13] Block = (o, mq), 256 thr = 4 waves; wave w ->
// 16x16 m-tile mq*4+w. All-bf16, no LDS staging in K-loop.
__global__ __launch_bounds__(256) void k_gemm(const unsigned short* __restrict__ xb,
                                              const unsigned short* __restrict__ tt,
                                              __half* __restrict__ mh) {
    const int blk = blockIdx.x;
    const int o   = blk & 127;
    const int mq  = blk >> 7;
    const int tid = threadIdx.x;
    const int wave = tid >> 6, lane = tid & 63;
    const int l15 = lane & 15, q = lane >> 4;

    __shared__ __half pmout[64][16];     // 2 KB repack buffer

    const int mt = mq * 4 + wave;
    const short8* ap = reinterpret_cast<const short8*>(&xb[(mt * 16 + l15) * INF + q * 8]);
    const short8* bp = reinterpret_cast<const short8*>(&tt[(o * 16 + l15) * INF + q * 8]);

    f32x4 acc = {0.f, 0.f, 0.f, 0.f};
    #pragma unroll 8
    for (int ks = 0; ks < 32; ++ks) {
        short8 a = ap[ks * 4];           // advance 32 k = 4 short8
        short8 b = bp[ks * 4];
        acc = __builtin_amdgcn_mfma_f32_16x16x32_bf16(a, b, acc, 0, 0, 0);
    }

    #pragma unroll
    for (int r = 0; r < 4; ++r)
        pmout[wave * 16 + q * 4 + r][l15] = __float2half(acc[r]);
    __syncthreads();

    if (tid < 128) {
        const int row = tid >> 1, hh = tid & 1;
        uint4 v = *reinterpret_cast<const uint4*>(&pmout[row][hh * 8]);
        *reinterpret_cast<uint4*>(&mh[o * (BATCH * KDIM) + (mq * 64 + row) * KDIM + hh * 8]) = v;
    }
}

// ---------------------------------------------------------------- k_pair
// [byte-identical to R13] 512 blocks = (o, qh) x 512 thr = 2 blocks/CU.
// i1 = l&15 -> 4 b1-rows {qh*64 + r*16 + i1}; bsel = w*4+(l>>4) -> 8 b2.
// Sl2 computed from registers during the pm load; 2 barriers total.
__global__ __launch_bounds__(512) void k_pair(const __half* __restrict__ mh,
                                              float* __restrict__ out) {
    const int blk = blockIdx.x;
    const int o   = blk & 127;
    const int qh  = blk >> 7;            // b1 quarter
    const int tid = threadIdx.x;
    const int lane = tid & 63, wave = tid >> 6;

    __shared__ __half2 pm[BATCH][8];     // 8 KB
    __shared__ float Sl2[BATCH];         // 1 KB
    __shared__ float part[32][64];       // 8 KB [bsel][row-local]

    if (tid < 256) {
        union { uint4 u[2]; __half2 hh[8]; } c;
        const uint4* src = reinterpret_cast<const uint4*>(&mh[o * (BATCH * KDIM) + tid * KDIM]);
        c.u[0] = src[0];
        c.u[1] = src[1];
        *reinterpret_cast<uint4*>(&pm[tid][0]) = c.u[0];
        *reinterpret_cast<uint4*>(&pm[tid][4]) = c.u[1];
        Sl2[tid] = L2E * ms_chain(c.hh, c.hh);   // min(a,a)=a: same chain order
    }
    __syncthreads();                     // barrier 1

    const int i1 = lane & 15;
    const int bsel = wave * 4 + (lane >> 4);     // 0..31, <=4-way co aliasing
    __half2 my[4][8];
    float ns[4];
    #pragma unroll
    for (int r = 0; r < 4; ++r) {
        const int b1 = qh * 64 + r * 16 + i1;
        union { uint4 u[2]; __half2 hh[8]; } c;
        c.u[0] = *reinterpret_cast<const uint4*>(&pm[b1][0]);
        c.u[1] = *reinterpret_cast<const uint4*>(&pm[b1][4]);
        #pragma unroll
        for (int j = 0; j < 8; ++j) my[r][j] = c.hh[j];
        ns[r] = -Sl2[b1];
    }

    float tot[4] = {0.f, 0.f, 0.f, 0.f};
    const int b2_lo = bsel * 8;
    #pragma unroll
    for (int b2 = b2_lo; b2 < b2_lo + 8; ++b2) {
        union { uint4 u[2]; __half2 hh[8]; } co;
        co.u[0] = *reinterpret_cast<const uint4*>(&pm[b2][0]);
        co.u[1] = *reinterpret_cast<const uint4*>(&pm[b2][4]);
        const float sb2 = Sl2[b2];
        #pragma unroll
        for (int r = 0; r < 4; ++r) {
            float msf = ms_chain(my[r], co.hh);
            // exp(-(S1+S2-2ms)) = exp2(2*L2E*ms - L2E*S1 - L2E*S2)
            float arg = fmaf(TL2E, msf, ns[r] - sb2);
            tot[r] += __builtin_amdgcn_exp2f(arg);   // self-pair: arg ~ ±ulp -> ~1
        }
    }
    #pragma unroll
    for (int r = 0; r < 4; ++r)
        part[bsel][r * 16 + i1] = tot[r];
    __syncthreads();                     // barrier 2

    // epilogue: 64 rows, sum 32 partials; -1 removes self-pair.
    if (tid < 64) {
        float s = -1.0f;
        #pragma unroll
        for (int j = 0; j < 32; ++j) s += part[j][tid];
        out[(qh * 64 + tid) * OCOLS + INF + o] = s;
    }
}

// ---------------------------------------------------------------- launch
extern "C" void kernel_launch(void* const* d_in, const int* in_sizes, int n_in,
                              void* d_out, int out_size, void* d_ws, size_t ws_size,
                              hipStream_t stream) {
    const float* x = (const float*)d_in[0];   // [256][1024]
    const float* T = (const float*)d_in[1];   // [1024][2048]
    float* out = (float*)d_out;               // [256][1152]

    unsigned short* xb = (unsigned short*)d_ws;                              // 512 KB
    unsigned short* tt = (unsigned short*)((char*)d_ws + (512u << 10));      // 4 MB
    __half*         mh = (__half*)((char*)d_ws + (512u << 10) + (4u << 20)); // 1 MB

    k_prep<<<864, 256, 0, stream>>>(x, T, xb, tt, out);
    k_gemm<<<512, 256, 0, stream>>>(xb, tt, mh);
    k_pair<<<512, 512, 0, stream>>>(mh, out);
}